// Round 3
// baseline (233.259 us; speedup 1.0000x reference)
//
#include <hip/hip_runtime.h>

// DCN: B=4, C=64, H=W=128, Cout=64, 3x3, pad=1, stride=1, dil=1
#define B_   4
#define C_   64
#define H_   128
#define W_   128
#define OC_  64
#define K_   9
#define OCH_ 18
#define CK_  576

#define S_   104              // LDS row stride in halfs (208 B, 16B-aligned rows)
#define SD_  (S_/2)           // 52 dwords
#define WCOLS 768             // 8 chunks * 96 padded cols

#define WPAD_HALFS (OC_*WCOLS)   // 49152
#define W0PAD_HALFS (32*WCOLS)   // 24576

using half8v  = __attribute__((ext_vector_type(8))) _Float16;
using half2v  = __attribute__((ext_vector_type(2))) _Float16;
using float4v = __attribute__((ext_vector_type(4))) float;

// ---------------------------------------------------------------------------
// k0: cast+pad weights to f16 in MFMA-chunk layout.
// col = cc*96 + kk*8 + cl  (channel c = cc*8+cl, tap kk; kk>=9 -> 0)
// ---------------------------------------------------------------------------
__global__ void k0_prep(const float* __restrict__ w, const float* __restrict__ ow,
                        _Float16* __restrict__ wpad, _Float16* __restrict__ w0pad) {
    int i = blockIdx.x * 256 + threadIdx.x;
    if (i < OC_ * WCOLS) {
        int oc = i / WCOLS, col = i - oc * WCOLS;
        int cc = col / 96, r = col - cc * 96;
        int kk = r >> 3, cl = r & 7;
        float v = 0.f;
        if (kk < 9) v = w[oc * CK_ + (cc * 8 + cl) * 9 + kk];
        wpad[i] = (_Float16)v;
    } else {
        int j = i - OC_ * WCOLS;
        if (j < 32 * WCOLS) {
            int rr = j / WCOLS, col = j - rr * WCOLS;
            int cc = col / 96, r = col - cc * 96;
            int kk = r >> 3, cl = r & 7;
            float v = 0.f;
            if (rr < OCH_ && kk < 9) v = ow[rr * CK_ + (cc * 8 + cl) * 9 + kk];
            w0pad[j] = (_Float16)v;
        }
    }
}

// ---------------------------------------------------------------------------
// k_fused: offset conv (phase 1, im2col MFMA -> offs in LDS) + bilinear
// sampling + main conv (phase 2, MFMA).  Block = 64 oc x 64 pix.
// XCD swizzle: xcd = bid&7 owns ho band [xcd*16, xcd*16+16) -> ~2.6 MB/XCD.
// ---------------------------------------------------------------------------
__global__ __launch_bounds__(256, 4) void k_fused(
    const float* __restrict__ x, const _Float16* __restrict__ wpad,
    const _Float16* __restrict__ w0pad, const float* __restrict__ bias,
    const float* __restrict__ ob, float* __restrict__ out)
{
    __shared__ __align__(16) _Float16 buf[2 * 64 * S_];   // 26624 B
    __shared__ float offs_lds[OCH_ * 64];                 // 4608 B

    _Float16* Wl = buf;              // phase1: 32 rows used; phase2: 64 rows
    _Float16* Pl = buf + 64 * S_;

    // ---- XCD-aware work decode (assumes round-robin bid -> bid&7) ----
    const int g   = blockIdx.x;
    const int xcd = g & 7;
    const int n   = g >> 3;          // 0..127 within XCD, b-major outermost
    const int hb  = n & 1;
    const int hol = (n >> 1) & 15;
    const int b   = n >> 5;
    const int ho  = xcd * 16 + hol;

    const int t = threadIdx.x, lane = t & 63, w = t >> 6;
    const int lr = lane & 15, q = lane >> 4;
    const int po = hb * 64 + lane;
    const float* xb = x + ((long)b << 20);

    // zero-pad P cols 72..95 once (never overwritten by either phase)
    for (int i = t; i < 64 * 12; i += 256) {
        int row = i / 12, j = i - row * 12;
        *(unsigned*)&Pl[row * S_ + 72 + 2 * j] = 0u;
    }

    // ================= phase 1: offset conv =================
    float4v oa0 = {0.f,0.f,0.f,0.f}, oa1 = {0.f,0.f,0.f,0.f};
    for (int cc = 0; cc < 8; cc++) {
        if (cc) __syncthreads();
        for (int i = t; i < 32 * 48; i += 256) {
            int oc = i / 48, cd = i - oc * 48;
            ((unsigned*)Wl)[oc * SD_ + cd] =
                ((const unsigned*)w0pad)[oc * (WCOLS / 2) + cc * 48 + cd];
        }
        const int c0 = cc * 8 + 2 * w;
        const float* xc0 = xb + ((long)c0 << 14);
        const float* xc1 = xc0 + (1 << 14);
        float v0[9], v1[9];
#pragma unroll
        for (int kk = 0; kk < 9; kk++) {
            int ky = kk / 3, kx = kk - 3 * ky;
            int gy = ho - 1 + ky, gx = po - 1 + kx;
            bool ok = ((unsigned)gy < (unsigned)H_) && ((unsigned)gx < (unsigned)W_);
            int idx = (gy << 7) + gx;
            v0[kk] = ok ? xc0[idx] : 0.f;
            v1[kk] = ok ? xc1[idx] : 0.f;
        }
#pragma unroll
        for (int kk = 0; kk < 9; kk++) {
            half2v hv = {(_Float16)v0[kk], (_Float16)v1[kk]};
            *(half2v*)&Pl[lane * S_ + kk * 8 + 2 * w] = hv;
        }
        __syncthreads();
#pragma unroll
        for (int ks = 0; ks < 3; ks++) {
            half8v a0 = *(const half8v*)&Wl[lr * S_ + ks * 32 + q * 8];
            half8v a1 = *(const half8v*)&Wl[(16 + lr) * S_ + ks * 32 + q * 8];
            half8v bv = *(const half8v*)&Pl[(w * 16 + lr) * S_ + ks * 32 + q * 8];
            oa0 = __builtin_amdgcn_mfma_f32_16x16x32_f16(a0, bv, oa0, 0, 0, 0);
            oa1 = __builtin_amdgcn_mfma_f32_16x16x32_f16(a1, bv, oa1, 0, 0, 0);
        }
    }
    {
        const int lpix = w * 16 + lr;
#pragma unroll
        for (int r = 0; r < 4; r++) {
            int ch = q * 4 + r;
            offs_lds[ch * 64 + lpix] = oa0[r] + ob[ch];
        }
#pragma unroll
        for (int r = 0; r < 4; r++) {
            int ch = 16 + q * 4 + r;
            if (ch < OCH_) offs_lds[ch * 64 + lpix] = oa1[r] + ob[ch];
        }
    }
    __syncthreads();

    // ================= bilinear meta (registers) =================
    int    ma0[9], ma1[9];
    half2v mwa[9], mwb[9];
#pragma unroll
    for (int kk = 0; kk < 9; kk++) {
        int ky = kk / 3, kx = kk - 3 * ky;
        float dy = offs_lds[(2 * kk) * 64 + lane];
        float dx = offs_lds[(2 * kk + 1) * 64 + lane];
        float py = (float)(ho - 1 + ky) + dy;
        float px = (float)(po - 1 + kx) + dx;
        float fy = floorf(py), fx = floorf(px);
        float ly = py - fy, lx = px - fx;
        int y0 = (int)fy, x0 = (int)fx;
        int y1 = y0 + 1, x1 = x0 + 1;
        float vy0 = ((unsigned)y0 < (unsigned)H_) ? 1.f : 0.f;
        float vy1 = ((unsigned)y1 < (unsigned)H_) ? 1.f : 0.f;
        float vx0 = ((unsigned)x0 < (unsigned)W_) ? 1.f : 0.f;
        float vx1 = ((unsigned)x1 < (unsigned)W_) ? 1.f : 0.f;
        float w00 = (1.f - ly) * (1.f - lx) * vy0 * vx0;
        float w01 = (1.f - ly) * lx * vy0 * vx1;
        float w10 = ly * (1.f - lx) * vy1 * vx0;
        float w11 = ly * lx * vy1 * vx1;
        int cy0 = min(max(y0, 0), H_ - 1);
        int cy1 = min(max(y1, 0), H_ - 1);
        int xl  = min(max(x0, 0), W_ - 2);
        bool noswap = (x0 == xl);   // fold x-clamp into weight swap
        float a = noswap ? w00 : w01, bb = noswap ? w01 : w00;
        float c = noswap ? w10 : w11, d  = noswap ? w11 : w10;
        mwa[kk] = {(_Float16)a, (_Float16)bb};
        mwb[kk] = {(_Float16)c, (_Float16)d};
        ma0[kk] = (cy0 << 7) + xl;
        ma1[kk] = (cy1 << 7) + xl;
    }

    // ================= phase 2: sample + main conv =================
    float4v a00 = {0.f,0.f,0.f,0.f}, a01 = {0.f,0.f,0.f,0.f};
    float4v a10 = {0.f,0.f,0.f,0.f}, a11 = {0.f,0.f,0.f,0.f};
    const int wm = w & 1, wn = w >> 1;

    for (int cc = 0; cc < 8; cc++) {
        __syncthreads();
        for (int i = t; i < 64 * 48; i += 256) {
            int oc = i / 48, cd = i - oc * 48;
            ((unsigned*)Wl)[oc * SD_ + cd] =
                ((const unsigned*)wpad)[oc * (WCOLS / 2) + cc * 48 + cd];
        }
        const int c0 = cc * 8 + 2 * w;
        const float* xc0 = xb + ((long)c0 << 14);
        const float* xc1 = xc0 + (1 << 14);
        float p0[9], p1[9];
#pragma unroll
        for (int kk = 0; kk < 9; kk++) {   // channel c0: batch 36 gathers
            int A0 = ma0[kk], A1 = ma1[kk];
            float u0 = (float)mwa[kk][0], u1 = (float)mwa[kk][1];
            float u2 = (float)mwb[kk][0], u3 = (float)mwb[kk][1];
            p0[kk] = xc0[A0] * u0 + xc0[A0 + 1] * u1 + xc0[A1] * u2 + xc0[A1 + 1] * u3;
        }
#pragma unroll
        for (int kk = 0; kk < 9; kk++) {   // channel c0+1
            int A0 = ma0[kk], A1 = ma1[kk];
            float u0 = (float)mwa[kk][0], u1 = (float)mwa[kk][1];
            float u2 = (float)mwb[kk][0], u3 = (float)mwb[kk][1];
            p1[kk] = xc1[A0] * u0 + xc1[A0 + 1] * u1 + xc1[A1] * u2 + xc1[A1 + 1] * u3;
        }
#pragma unroll
        for (int kk = 0; kk < 9; kk++) {
            half2v hv = {(_Float16)p0[kk], (_Float16)p1[kk]};
            *(half2v*)&Pl[lane * S_ + kk * 8 + 2 * w] = hv;
        }
        __syncthreads();
#pragma unroll
        for (int ks = 0; ks < 3; ks++) {
            half8v A0 = *(const half8v*)&Wl[(wm * 32 + lr) * S_ + ks * 32 + q * 8];
            half8v A1 = *(const half8v*)&Wl[(wm * 32 + 16 + lr) * S_ + ks * 32 + q * 8];
            half8v B0 = *(const half8v*)&Pl[(wn * 32 + lr) * S_ + ks * 32 + q * 8];
            half8v B1 = *(const half8v*)&Pl[(wn * 32 + 16 + lr) * S_ + ks * 32 + q * 8];
            a00 = __builtin_amdgcn_mfma_f32_16x16x32_f16(A0, B0, a00, 0, 0, 0);
            a01 = __builtin_amdgcn_mfma_f32_16x16x32_f16(A0, B1, a01, 0, 0, 0);
            a10 = __builtin_amdgcn_mfma_f32_16x16x32_f16(A1, B0, a10, 0, 0, 0);
            a11 = __builtin_amdgcn_mfma_f32_16x16x32_f16(A1, B1, a11, 0, 0, 0);
        }
    }

    // ---- epilogue ----
    const int pixc = hb * 64 + wn * 32 + lr;
#pragma unroll
    for (int r = 0; r < 4; r++) {
        int oc0 = wm * 32 + q * 4 + r;
        int oc1 = oc0 + 16;
        float* o0 = out + (((long)(b * OC_ + oc0)) << 14) + (ho << 7);
        float* o1 = out + (((long)(b * OC_ + oc1)) << 14) + (ho << 7);
        o0[pixc]      = a00[r] + bias[oc0];
        o0[pixc + 16] = a01[r] + bias[oc0];
        o1[pixc]      = a10[r] + bias[oc1];
        o1[pixc + 16] = a11[r] + bias[oc1];
    }
}

// ---------------------------------------------------------------------------
extern "C" void kernel_launch(void* const* d_in, const int* in_sizes, int n_in,
                              void* d_out, int out_size, void* d_ws, size_t ws_size,
                              hipStream_t stream) {
    const float* x  = (const float*)d_in[0];
    const float* wt = (const float*)d_in[1];
    const float* bi = (const float*)d_in[2];
    const float* ow = (const float*)d_in[3];
    const float* ob = (const float*)d_in[4];
    float* out = (float*)d_out;

    _Float16* wpad  = (_Float16*)d_ws;
    _Float16* w0pad = wpad + WPAD_HALFS;

    k0_prep<<<(OC_ * WCOLS + 32 * WCOLS + 255) / 256, 256, 0, stream>>>(wt, ow, wpad, w0pad);
    k_fused<<<B_ * H_ * 2, 256, 0, stream>>>(x, wpad, w0pad, bi, ob, out);
}

// Round 4
// 188.796 us; speedup vs baseline: 1.2355x; 1.2355x over previous
//
#include <hip/hip_runtime.h>

// DCN: B=4, C=64, H=W=128, Cout=64, 3x3, pad=1, stride=1, dil=1
#define B_   4
#define C_   64
#define H_   128
#define W_   128
#define OC_  64
#define K_   9
#define OCH_ 18
#define CK_  576

#define S_    104            // Pl row stride in halfs (208 B, 16B-aligned)
#define WCOLS 768            // 8 chunks * 96 padded cols
#define XSW   72             // x window cols (64 + 2*4 halo)
#define XSH   9              // x window rows (ho-4 .. ho+4)
#define XSC   (XSH*XSW)      // 648 floats per channel

#define WPAD_HALFS (OC_*WCOLS)   // 49152

using half8v  = __attribute__((ext_vector_type(8))) _Float16;
using half2v  = __attribute__((ext_vector_type(2))) _Float16;
using float4v = __attribute__((ext_vector_type(4))) float;

// ---------------------------------------------------------------------------
// k0: cast+pad weights to f16 in MFMA-chunk layout.
// col = cc*96 + kk*8 + cl  (channel c = cc*8+cl, tap kk; kk>=9 -> 0)
// ---------------------------------------------------------------------------
__global__ void k0_prep(const float* __restrict__ w, const float* __restrict__ ow,
                        _Float16* __restrict__ wpad, _Float16* __restrict__ w0pad) {
    int i = blockIdx.x * 256 + threadIdx.x;
    if (i < OC_ * WCOLS) {
        int oc = i / WCOLS, col = i - oc * WCOLS;
        int cc = col / 96, r = col - cc * 96;
        int kk = r >> 3, cl = r & 7;
        float v = 0.f;
        if (kk < 9) v = w[oc * CK_ + (cc * 8 + cl) * 9 + kk];
        wpad[i] = (_Float16)v;
    } else {
        int j = i - OC_ * WCOLS;
        if (j < 32 * WCOLS) {
            int rr = j / WCOLS, col = j - rr * WCOLS;
            int cc = col / 96, r = col - cc * 96;
            int kk = r >> 3, cl = r & 7;
            float v = 0.f;
            if (rr < OCH_ && kk < 9) v = ow[rr * CK_ + (cc * 8 + cl) * 9 + kk];
            w0pad[j] = (_Float16)v;
        }
    }
}

// ---------------------------------------------------------------------------
// k_fused: phase1 offset conv (im2col MFMA, A-frags straight from L2) ->
// offs in LDS -> phase2: stage x window in LDS, bilinear-sample FROM LDS,
// MFMA main conv.  Block = 64 oc x 64 pix.  LDS 38.7 KB -> 4 blocks/CU.
// ---------------------------------------------------------------------------
__global__ __launch_bounds__(256, 4) void k_fused(
    const float* __restrict__ x, const _Float16* __restrict__ wpad,
    const _Float16* __restrict__ w0pad, const float* __restrict__ bias,
    const float* __restrict__ ob, float* __restrict__ out)
{
    __shared__ __align__(16) _Float16 Pl[64 * S_];   // 13312 B
    __shared__ __align__(16) float    xs[8 * XSC];   // 20736 B
    __shared__ float offs_lds[OCH_ * 64];            //  4608 B

    // ---- XCD-aware work decode (round-robin bid -> bid&7 heuristic) ----
    const int g   = blockIdx.x;
    const int xcd = g & 7;
    const int n   = g >> 3;
    const int hb  = n & 1;
    const int hol = (n >> 1) & 15;
    const int b   = n >> 5;
    const int ho  = xcd * 16 + hol;

    const int t = threadIdx.x, lane = t & 63, w = t >> 6;
    const int lr = lane & 15, q = lane >> 4;
    const int po = hb * 64 + lane;
    const int start = hb * 64 - 4;                   // window col origin
    const float* xb = x + ((long)b << 20);

    // zero-pad Pl cols 72..95 once (disjoint from data writes; read after sync)
    for (int i = t; i < 64 * 12; i += 256) {
        int row = i / 12, j = i - row * 12;
        *(unsigned*)&Pl[row * S_ + 72 + 2 * j] = 0u;
    }

    // ================= phase 1: offset conv =================
    float4v oa0 = {0.f,0.f,0.f,0.f}, oa1 = {0.f,0.f,0.f,0.f};
    for (int cc = 0; cc < 8; cc++) {
        if (cc) __syncthreads();                     // Pl reuse
        const int c0 = cc * 8 + 2 * w;
        const float* xc0 = xb + ((long)c0 << 14);
        const float* xc1 = xc0 + (1 << 14);
        float v0[9], v1[9];
#pragma unroll
        for (int kk = 0; kk < 9; kk++) {
            int ky = kk / 3, kx = kk - 3 * ky;
            int gy = ho - 1 + ky, gx = po - 1 + kx;
            bool okp = ((unsigned)gy < (unsigned)H_) && ((unsigned)gx < (unsigned)W_);
            int idx = (gy << 7) + gx;
            v0[kk] = okp ? xc0[idx] : 0.f;
            v1[kk] = okp ? xc1[idx] : 0.f;
        }
#pragma unroll
        for (int kk = 0; kk < 9; kk++) {
            half2v hv = {(_Float16)v0[kk], (_Float16)v1[kk]};
            *(half2v*)&Pl[lane * S_ + kk * 8 + 2 * w] = hv;
        }
        __syncthreads();
#pragma unroll
        for (int ks = 0; ks < 3; ks++) {
            half8v a0 = *(const half8v*)&w0pad[lr * WCOLS + cc * 96 + ks * 32 + q * 8];
            half8v a1 = *(const half8v*)&w0pad[(16 + lr) * WCOLS + cc * 96 + ks * 32 + q * 8];
            half8v bv = *(const half8v*)&Pl[(w * 16 + lr) * S_ + ks * 32 + q * 8];
            oa0 = __builtin_amdgcn_mfma_f32_16x16x32_f16(a0, bv, oa0, 0, 0, 0);
            oa1 = __builtin_amdgcn_mfma_f32_16x16x32_f16(a1, bv, oa1, 0, 0, 0);
        }
    }
    {
        const int lpix = w * 16 + lr;
#pragma unroll
        for (int r = 0; r < 4; r++) {
            int ch = q * 4 + r;
            offs_lds[ch * 64 + lpix] = oa0[r] + ob[ch];
        }
#pragma unroll
        for (int r = 0; r < 4; r++) {
            int ch = 16 + q * 4 + r;
            if (ch < OCH_) offs_lds[ch * 64 + lpix] = oa1[r] + ob[ch];
        }
    }
    __syncthreads();

    // ================= bilinear meta (LDS-window offsets) =================
    int    offA[9], offB[9];
    half2v mwa[9], mwb[9];
    unsigned okm = 0;
#pragma unroll
    for (int kk = 0; kk < 9; kk++) {
        int ky = kk / 3, kx = kk - 3 * ky;
        float dy = offs_lds[(2 * kk) * 64 + lane];
        float dx = offs_lds[(2 * kk + 1) * 64 + lane];
        float py = (float)(ho - 1 + ky) + dy;
        float px = (float)(po - 1 + kx) + dx;
        float fy = floorf(py), fx = floorf(px);
        float ly = py - fy, lx = px - fx;
        int y0 = (int)fy, x0 = (int)fx;
        int y1 = y0 + 1, x1 = x0 + 1;
        float vy0 = ((unsigned)y0 < (unsigned)H_) ? 1.f : 0.f;
        float vy1 = ((unsigned)y1 < (unsigned)H_) ? 1.f : 0.f;
        float vx0 = ((unsigned)x0 < (unsigned)W_) ? 1.f : 0.f;
        float vx1 = ((unsigned)x1 < (unsigned)W_) ? 1.f : 0.f;
        float w00 = (1.f - ly) * (1.f - lx) * vy0 * vx0;
        float w01 = (1.f - ly) * lx * vy0 * vx1;
        float w10 = ly * (1.f - lx) * vy1 * vx0;
        float w11 = ly * lx * vy1 * vx1;
        int cy0 = min(max(y0, 0), H_ - 1);
        int cy1 = min(max(y1, 0), H_ - 1);
        int xl  = min(max(x0, 0), W_ - 2);
        bool noswap = (x0 == xl);            // fold x-clamp into weight swap
        float a = noswap ? w00 : w01, bb = noswap ? w01 : w00;
        float c = noswap ? w10 : w11, d  = noswap ? w11 : w10;
        mwa[kk] = {(_Float16)a, (_Float16)bb};
        mwb[kk] = {(_Float16)c, (_Float16)d};
        int sy0 = cy0 - (ho - 4);
        int sy1 = cy1 - (ho - 4);
        int sx  = xl - start;
        bool ok = ((unsigned)sy0 < (unsigned)XSH) && ((unsigned)sy1 < (unsigned)XSH)
               && ((unsigned)sx < (unsigned)(XSW - 1));
        okm |= (ok ? 1u : 0u) << kk;
        offA[kk] = sy0 * XSW + sx;
        offB[kk] = sy1 * XSW + sx;
    }

    // ================= phase 2: stage window + sample-from-LDS + MFMA =====
    float4v a00 = {0.f,0.f,0.f,0.f}, a01 = {0.f,0.f,0.f,0.f};
    float4v a10 = {0.f,0.f,0.f,0.f}, a11 = {0.f,0.f,0.f,0.f};
    const int wm = w & 1, wn = w >> 1;

    for (int cc = 0; cc < 8; cc++) {
        __syncthreads();                             // xs & Pl reuse
        // stage x window: 8 ch x 9 rows x 72 cols, coalesced
        for (int i = t; i < 8 * XSC; i += 256) {
            int c  = i / XSC;
            int rj = i - c * XSC;
            int r  = rj / XSW;
            int j  = rj - r * XSW;
            int gy = ho - 4 + r, gx = start + j;
            bool okp = ((unsigned)gy < (unsigned)H_) && ((unsigned)gx < (unsigned)W_);
            xs[i] = okp ? xb[((long)(cc * 8 + c) << 14) + (gy << 7) + gx] : 0.f;
        }
        __syncthreads();
        // sample (wave w -> channels 2w, 2w+1)
        const float* xs0 = xs + (2 * w) * XSC;
        const float* xs1 = xs0 + XSC;
        float p0[9], p1[9];
        if (__all(okm == 0x1FFu)) {
#pragma unroll
            for (int kk = 0; kk < 9; kk++) {
                int A = offA[kk], Bo = offB[kk];
                float u0 = (float)mwa[kk][0], u1 = (float)mwa[kk][1];
                float u2 = (float)mwb[kk][0], u3 = (float)mwb[kk][1];
                p0[kk] = xs0[A] * u0 + xs0[A + 1] * u1 + xs0[Bo] * u2 + xs0[Bo + 1] * u3;
                p1[kk] = xs1[A] * u0 + xs1[A + 1] * u1 + xs1[Bo] * u2 + xs1[Bo + 1] * u3;
            }
        } else {
            // rare: recompute addresses, gather from global (clamped, valid)
            const float* xc0 = xb + ((long)(cc * 8 + 2 * w) << 14);
            const float* xc1 = xc0 + (1 << 14);
#pragma unroll
            for (int kk = 0; kk < 9; kk++) {
                int ky = kk / 3, kx = kk - 3 * ky;
                float dy = offs_lds[(2 * kk) * 64 + lane];
                float dx = offs_lds[(2 * kk + 1) * 64 + lane];
                float py = (float)(ho - 1 + ky) + dy;
                float px = (float)(po - 1 + kx) + dx;
                int y0 = (int)floorf(py), x0 = (int)floorf(px);
                int cy0 = min(max(y0, 0), H_ - 1);
                int cy1 = min(max(y0 + 1, 0), H_ - 1);
                int xl  = min(max(x0, 0), W_ - 2);
                int ga = (cy0 << 7) + xl, gb = (cy1 << 7) + xl;
                float u0 = (float)mwa[kk][0], u1 = (float)mwa[kk][1];
                float u2 = (float)mwb[kk][0], u3 = (float)mwb[kk][1];
                p0[kk] = xc0[ga] * u0 + xc0[ga + 1] * u1 + xc0[gb] * u2 + xc0[gb + 1] * u3;
                p1[kk] = xc1[ga] * u0 + xc1[ga + 1] * u1 + xc1[gb] * u2 + xc1[gb + 1] * u3;
            }
        }
#pragma unroll
        for (int kk = 0; kk < 9; kk++) {
            half2v hv = {(_Float16)p0[kk], (_Float16)p1[kk]};
            *(half2v*)&Pl[lane * S_ + kk * 8 + 2 * w] = hv;
        }
        __syncthreads();
#pragma unroll
        for (int ks = 0; ks < 3; ks++) {
            half8v A0 = *(const half8v*)&wpad[(wm * 32 + lr) * WCOLS + cc * 96 + ks * 32 + q * 8];
            half8v A1 = *(const half8v*)&wpad[(wm * 32 + 16 + lr) * WCOLS + cc * 96 + ks * 32 + q * 8];
            half8v B0 = *(const half8v*)&Pl[(wn * 32 + lr) * S_ + ks * 32 + q * 8];
            half8v B1 = *(const half8v*)&Pl[(wn * 32 + 16 + lr) * S_ + ks * 32 + q * 8];
            a00 = __builtin_amdgcn_mfma_f32_16x16x32_f16(A0, B0, a00, 0, 0, 0);
            a01 = __builtin_amdgcn_mfma_f32_16x16x32_f16(A0, B1, a01, 0, 0, 0);
            a10 = __builtin_amdgcn_mfma_f32_16x16x32_f16(A1, B0, a10, 0, 0, 0);
            a11 = __builtin_amdgcn_mfma_f32_16x16x32_f16(A1, B1, a11, 0, 0, 0);
        }
    }

    // ---- epilogue ----
    const int pixc = hb * 64 + wn * 32 + lr;
#pragma unroll
    for (int r = 0; r < 4; r++) {
        int oc0 = wm * 32 + q * 4 + r;
        int oc1 = oc0 + 16;
        float* o0 = out + (((long)(b * OC_ + oc0)) << 14) + (ho << 7);
        float* o1 = out + (((long)(b * OC_ + oc1)) << 14) + (ho << 7);
        o0[pixc]      = a00[r] + bias[oc0];
        o0[pixc + 16] = a01[r] + bias[oc0];
        o1[pixc]      = a10[r] + bias[oc1];
        o1[pixc + 16] = a11[r] + bias[oc1];
    }
}

// ---------------------------------------------------------------------------
extern "C" void kernel_launch(void* const* d_in, const int* in_sizes, int n_in,
                              void* d_out, int out_size, void* d_ws, size_t ws_size,
                              hipStream_t stream) {
    const float* x  = (const float*)d_in[0];
    const float* wt = (const float*)d_in[1];
    const float* bi = (const float*)d_in[2];
    const float* ow = (const float*)d_in[3];
    const float* ob = (const float*)d_in[4];
    float* out = (float*)d_out;

    _Float16* wpad  = (_Float16*)d_ws;
    _Float16* w0pad = wpad + WPAD_HALFS;

    k0_prep<<<(OC_ * WCOLS + 32 * WCOLS + 255) / 256, 256, 0, stream>>>(wt, ow, wpad, w0pad);
    k_fused<<<B_ * H_ * 2, 256, 0, stream>>>(x, wpad, w0pad, bi, ob, out);
}